// Round 4
// baseline (173.043 us; speedup 1.0000x reference)
//
#include <hip/hip_runtime.h>
#include <math.h>

#define TOKENS 16384
#define HIDDEN 2048
#define NEXP   64
#define MBLK   64                 // tokens per block (= lanes per wave)
#define NCHUNK 4                  // K chunks — MUST stay 4 to bit-match R1 logits
#define KCH    512                // k per chunk
#define KBLK   16                 // k per staged round
#define NTILE  (KCH / KBLK)       // 32 rounds
#define EHALF  32                 // experts per wave (wave&1 selects half)
#define XPAD   20                 // x tile row stride (floats), 16B aligned
#define RPAD   68                 // red row stride (floats), 16B aligned
#define TOPK   6
#define NGROUP 8
#define TOPKG  3

__global__ __launch_bounds__(512, 2)
void moe_gate_kernel(const float* __restrict__ X, const float* __restrict__ W,
                     float* __restrict__ out, int half_out)
{
    __shared__ float xs[8][MBLK][XPAD];   // 8*64*20*4 = 40960 B (wave-private tiles)
    __shared__ float red[MBLK][RPAD];     // 64*68*4  = 17408 B   (58.4 KB total)

    const int tid   = threadIdx.x;
    const int wv    = __builtin_amdgcn_readfirstlane(tid >> 6); // uniform wave id 0..7
    const int lane  = tid & 63;                                  // lane = token-in-block
    const int chunk = wv >> 1;                                   // K chunk 0..3
    const int eh    = wv & 1;                                    // expert half 0..1
    const int e0    = eh * EHALF;
    const int kb0   = chunk * KCH;
    const int row0  = blockIdx.x * MBLK;

    float acc[EHALF];
#pragma unroll
    for (int j = 0; j < EHALF; ++j) acc[j] = 0.f;

    const float* xb = X + (size_t)row0 * HIDDEN + kb0;

    // staging mapping: 4 lanes per row (float4 each), 4 row-groups of 16
    const int sr = lane >> 2;          // 0..15
    const int sc = lane & 3;           // 0..3

    float4 px[4];
#pragma unroll
    for (int it = 0; it < 4; ++it)
        px[it] = *(const float4*)(xb + (size_t)(it * 16 + sr) * HIDDEN + sc * 4);

#pragma unroll 1
    for (int t = 0; t < NTILE; ++t) {
        // store prefetched x tile to this wave's private LDS tile
#pragma unroll
        for (int it = 0; it < 4; ++it) {
            float* d = &xs[wv][it * 16 + sr][sc * 4];
            d[0] = px[it].x; d[1] = px[it].y; d[2] = px[it].z; d[3] = px[it].w;
        }
        // same-wave write->cross-lane-read fence (belt & suspenders; cheap)
        asm volatile("s_waitcnt lgkmcnt(0)" ::: "memory");

        // prefetch next round's x tile (vmcnt domain; overlaps compute)
        if (t + 1 < NTILE) {
            const float* xt = xb + (t + 1) * KBLK;
#pragma unroll
            for (int it = 0; it < 4; ++it)
                px[it] = *(const float4*)(xt + (size_t)(it * 16 + sr) * HIDDEN + sc * 4);
        }

        // each lane reads ITS token's 16 k-values
        float4 xq[4];
#pragma unroll
        for (int c = 0; c < 4; ++c)
            xq[c] = *(const float4*)&xs[wv][lane][c * 4];

        // W segments: fully wave-uniform addresses -> scalar loads
        const float* wk = W + (size_t)kb0 + (size_t)t * KBLK;
#pragma unroll
        for (int j = 0; j < EHALF; ++j) {
            const float4* wr = (const float4*)(wk + (size_t)(e0 + j) * HIDDEN);
            float4 w0 = wr[0], w1 = wr[1], w2 = wr[2], w3 = wr[3];
            float a = acc[j];
            a = fmaf(xq[0].x, w0.x, a); a = fmaf(xq[0].y, w0.y, a);
            a = fmaf(xq[0].z, w0.z, a); a = fmaf(xq[0].w, w0.w, a);
            a = fmaf(xq[1].x, w1.x, a); a = fmaf(xq[1].y, w1.y, a);
            a = fmaf(xq[1].z, w1.z, a); a = fmaf(xq[1].w, w1.w, a);
            a = fmaf(xq[2].x, w2.x, a); a = fmaf(xq[2].y, w2.y, a);
            a = fmaf(xq[2].z, w2.z, a); a = fmaf(xq[2].w, w2.w, a);
            a = fmaf(xq[3].x, w3.x, a); a = fmaf(xq[3].y, w3.y, a);
            a = fmaf(xq[3].z, w3.z, a); a = fmaf(xq[3].w, w3.w, a);
            acc[j] = a;
        }
    }

    // ---- cross-chunk reduction, chunk order 0,1,2,3 => tree ((c0+c1)+c2)+c3
    // (bit-identical to R1's wave-order reduction; halves touch disjoint cols)
    __syncthreads();
    if (chunk == 0) {
#pragma unroll
        for (int q = 0; q < EHALF / 4; ++q) {
            float4 v = make_float4(acc[q * 4], acc[q * 4 + 1], acc[q * 4 + 2], acc[q * 4 + 3]);
            *(float4*)&red[lane][e0 + q * 4] = v;
        }
    }
    __syncthreads();
    for (int c = 1; c < NCHUNK; ++c) {
        if (chunk == c) {
#pragma unroll
            for (int q = 0; q < EHALF / 4; ++q) {
                float4 r = *(const float4*)&red[lane][e0 + q * 4];
                r.x += acc[q * 4];     r.y += acc[q * 4 + 1];
                r.z += acc[q * 4 + 2]; r.w += acc[q * 4 + 3];
                *(float4*)&red[lane][e0 + q * 4] = r;
            }
        }
        __syncthreads();
    }

    // ---- routing: one lane per token (wave 0) — identical code to R1
    if (tid < MBLK) {
        const int t = tid;
        float s[NEXP];
        float m = -INFINITY;
#pragma unroll
        for (int e = 0; e < NEXP; ++e) { s[e] = red[t][e]; m = fmaxf(m, s[e]); }
        float sum = 0.f;
#pragma unroll
        for (int e = 0; e < NEXP; ++e) { s[e] = __expf(s[e] - m); sum += s[e]; }
        float inv = 1.f / sum;
#pragma unroll
        for (int e = 0; e < NEXP; ++e) s[e] *= inv;

        float gs[NGROUP];
#pragma unroll
        for (int g = 0; g < NGROUP; ++g) {
            float gm = s[g * 8];
#pragma unroll
            for (int q = 1; q < 8; ++q) gm = fmaxf(gm, s[g * 8 + q]);
            gs[g] = gm;
        }
        unsigned gmask = 0;
        for (int r = 0; r < TOPKG; ++r) {
            int bg = 0; float bv = -INFINITY;
#pragma unroll
            for (int g = 0; g < NGROUP; ++g) {
                bool avail = !((gmask >> g) & 1);
                if (avail && gs[g] > bv) { bv = gs[g]; bg = g; }
            }
            gmask |= 1u << bg;
        }
        unsigned long long chosen = 0ull;
        const int tok = row0 + t;
        for (int k = 0; k < TOPK; ++k) {
            int be = 0; float bv = -INFINITY;
#pragma unroll
            for (int e = 0; e < NEXP; ++e) {
                float v = ((gmask >> (e >> 3)) & 1u) ? s[e] : 0.f;
                bool avail = !((chosen >> e) & 1ull);
                if (avail && v > bv) { bv = v; be = e; }
            }
            chosen |= 1ull << be;
            out[(size_t)tok * TOPK + k] = (float)be;                 // idx as f32
            out[(size_t)half_out + (size_t)tok * TOPK + k] = bv;     // weight
        }
    }
}

extern "C" void kernel_launch(void* const* d_in, const int* in_sizes, int n_in,
                              void* d_out, int out_size, void* d_ws, size_t ws_size,
                              hipStream_t stream)
{
    const float* x = (const float*)d_in[0];
    const float* w = (const float*)d_in[1];
    float* out = (float*)d_out;
    const int half_out = out_size / 2;   // 98304 = 16384*6

    dim3 grid(TOKENS / MBLK);            // 256 blocks
    dim3 block(512);                     // 8 waves: (chunk, expert-half)
    moe_gate_kernel<<<grid, block, 0, stream>>>(x, w, out, half_out);
}

// Round 5
// 135.032 us; speedup vs baseline: 1.2815x; 1.2815x over previous
//
#include <hip/hip_runtime.h>
#include <math.h>

#define TOKENS 16384
#define HIDDEN 2048
#define NEXP   64
#define MBLK   64                 // tokens per block
#define NCHUNK 4                  // K chunks — wave=chunk; keeps R1 bit-exact logits
#define KCH    512                // k per chunk
#define KBLK   16                 // k per staged round
#define NTILE  (KCH / KBLK)       // 32 rounds
#define XPAD   20                 // row stride in floats: 80B -> conflict-free b128
#define RPAD   68
#define TOPK   6
#define NGROUP 8
#define TOPKG  3

__global__ __launch_bounds__(256, 1)
void moe_gate_kernel(const float* __restrict__ X, const float* __restrict__ W,
                     float* __restrict__ out, int half_out)
{
    __shared__ float xs[NCHUNK][MBLK][XPAD];  // 20480 B (wave-private tiles)
    __shared__ float ws[NCHUNK][NEXP][XPAD];  // 20480 B
    __shared__ float red[MBLK][RPAD];         // 17408 B  (58368 total)

    const int tid  = threadIdx.x;
    const int wv   = __builtin_amdgcn_readfirstlane(tid >> 6); // wave = K chunk 0..3
    const int lane = tid & 63;
    const int lr   = lane >> 3;       // 0..7 token-row group
    const int lc   = lane & 7;        // 0..7 expert-col group
    const int row0 = blockIdx.x * MBLK;
    const int kb0  = wv * KCH;

    // staging: 4 lanes per row (one float4 each), 4 row-groups of 16
    const int sr = lane >> 2;         // 0..15
    const int sc = lane & 3;          // 0..3

    float acc[8][8];
#pragma unroll
    for (int i = 0; i < 8; ++i)
#pragma unroll
        for (int j = 0; j < 8; ++j) acc[i][j] = 0.f;

    const float* xb = X + (size_t)row0 * HIDDEN + kb0;
    const float* wb = W + kb0;

    float4 px[4], pw[4];
#pragma unroll
    for (int it = 0; it < 4; ++it) {
        px[it] = *(const float4*)(xb + (size_t)(it * 16 + sr) * HIDDEN + sc * 4);
        pw[it] = *(const float4*)(wb + (size_t)(it * 16 + sr) * HIDDEN + sc * 4);
    }

#pragma unroll 1
    for (int t = 0; t < NTILE; ++t) {
        // stage this round's tiles (wave-private; DS in-order per wave, compiler
        // inserts the lgkmcnt waits — no barrier, no manual fence)
#pragma unroll
        for (int it = 0; it < 4; ++it) {
            *(float4*)&xs[wv][it * 16 + sr][sc * 4] = px[it];
            *(float4*)&ws[wv][it * 16 + sr][sc * 4] = pw[it];
        }

        // prefetch next round (vmcnt domain — hides under this round's FMAs)
        if (t + 1 < NTILE) {
            const float* xt = xb + (t + 1) * KBLK;
            const float* wt = wb + (t + 1) * KBLK;
#pragma unroll
            for (int it = 0; it < 4; ++it) {
                px[it] = *(const float4*)(xt + (size_t)(it * 16 + sr) * HIDDEN + sc * 4);
                pw[it] = *(const float4*)(wt + (size_t)(it * 16 + sr) * HIDDEN + sc * 4);
            }
        }

        // compute: 4 k4-groups; 16 conflict-free ds_read_b128 per 256 FMA-instr
#pragma unroll
        for (int k4 = 0; k4 < 4; ++k4) {
            float4 a[8], b[8];
#pragma unroll
            for (int i = 0; i < 8; ++i)
                a[i] = *(const float4*)&xs[wv][i * 8 + lr][k4 * 4];
#pragma unroll
            for (int j = 0; j < 8; ++j)
                b[j] = *(const float4*)&ws[wv][j * 8 + lc][k4 * 4];
#pragma unroll
            for (int i = 0; i < 8; ++i)
#pragma unroll
                for (int j = 0; j < 8; ++j) {
                    float v = acc[i][j];
                    v = fmaf(a[i].x, b[j].x, v);
                    v = fmaf(a[i].y, b[j].y, v);
                    v = fmaf(a[i].z, b[j].z, v);
                    v = fmaf(a[i].w, b[j].w, v);
                    acc[i][j] = v;
                }
        }
    }

    // ---- cross-chunk reduction, order 0,1,2,3 => ((c0+c1)+c2)+c3 (R1-exact)
    __syncthreads();
    if (wv == 0) {
#pragma unroll
        for (int i = 0; i < 8; ++i)
#pragma unroll
            for (int j = 0; j < 8; ++j)
                red[i * 8 + lr][j * 8 + lc] = acc[i][j];
    }
    __syncthreads();
    for (int c = 1; c < NCHUNK; ++c) {
        if (wv == c) {
#pragma unroll
            for (int i = 0; i < 8; ++i)
#pragma unroll
                for (int j = 0; j < 8; ++j)
                    red[i * 8 + lr][j * 8 + lc] += acc[i][j];
        }
        __syncthreads();
    }

    // ---- routing: one lane per token — identical code to R1
    if (tid < MBLK) {
        const int t = tid;
        float s[NEXP];
        float m = -INFINITY;
#pragma unroll
        for (int e = 0; e < NEXP; ++e) { s[e] = red[t][e]; m = fmaxf(m, s[e]); }
        float sum = 0.f;
#pragma unroll
        for (int e = 0; e < NEXP; ++e) { s[e] = __expf(s[e] - m); sum += s[e]; }
        float inv = 1.f / sum;
#pragma unroll
        for (int e = 0; e < NEXP; ++e) s[e] *= inv;

        float gs[NGROUP];
#pragma unroll
        for (int g = 0; g < NGROUP; ++g) {
            float gm = s[g * 8];
#pragma unroll
            for (int q = 1; q < 8; ++q) gm = fmaxf(gm, s[g * 8 + q]);
            gs[g] = gm;
        }
        unsigned gmask = 0;
        for (int r = 0; r < TOPKG; ++r) {
            int bg = 0; float bv = -INFINITY;
#pragma unroll
            for (int g = 0; g < NGROUP; ++g) {
                bool avail = !((gmask >> g) & 1);
                if (avail && gs[g] > bv) { bv = gs[g]; bg = g; }
            }
            gmask |= 1u << bg;
        }
        unsigned long long chosen = 0ull;
        const int tok = row0 + t;
        for (int k = 0; k < TOPK; ++k) {
            int be = 0; float bv = -INFINITY;
#pragma unroll
            for (int e = 0; e < NEXP; ++e) {
                float v = ((gmask >> (e >> 3)) & 1u) ? s[e] : 0.f;
                bool avail = !((chosen >> e) & 1ull);
                if (avail && v > bv) { bv = v; be = e; }
            }
            chosen |= 1ull << be;
            out[(size_t)tok * TOPK + k] = (float)be;                 // idx as f32
            out[(size_t)half_out + (size_t)tok * TOPK + k] = bv;     // weight
        }
    }
}

extern "C" void kernel_launch(void* const* d_in, const int* in_sizes, int n_in,
                              void* d_out, int out_size, void* d_ws, size_t ws_size,
                              hipStream_t stream)
{
    const float* x = (const float*)d_in[0];
    const float* w = (const float*)d_in[1];
    float* out = (float*)d_out;
    const int half_out = out_size / 2;   // 98304 = 16384*6

    dim3 grid(TOKENS / MBLK);            // 256 blocks
    dim3 block(256);                     // 4 waves = 4 K chunks
    moe_gate_kernel<<<grid, block, 0, stream>>>(x, w, out, half_out);
}

// Round 6
// 132.224 us; speedup vs baseline: 1.3087x; 1.0212x over previous
//
#include <hip/hip_runtime.h>
#include <math.h>

#define TOKENS 16384
#define HIDDEN 2048
#define NEXP   64
#define MBLK   32                 // tokens per block
#define NCHUNK 4                  // K chunks — wave=chunk; keeps R1 bit-exact logits
#define KCH    512                // k per chunk
#define KBLK   16                 // k per staged round
#define NTILE  (KCH / KBLK)       // 32 rounds
#define XPAD   20                 // row stride in floats: conflict-balanced for b128
#define RPAD   68
#define TOPK   6
#define NGROUP 8
#define TOPKG  3

__global__ __launch_bounds__(256, 2)
void moe_gate_kernel(const float* __restrict__ X, const float* __restrict__ W,
                     float* __restrict__ out, int half_out)
{
    __shared__ float xs[NCHUNK][MBLK][XPAD];  // 4*32*20*4 = 10240 B (wave-private)
    __shared__ float ws[NCHUNK][NEXP][XPAD];  // 4*64*20*4 = 20480 B (wave-private)
    __shared__ float red[MBLK][RPAD];         // 32*68*4  =  8704 B  (39424 total)

    const int tid  = threadIdx.x;
    const int wv   = __builtin_amdgcn_readfirstlane(tid >> 6); // wave = K chunk 0..3
    const int lane = tid & 63;
    const int lr   = lane >> 3;       // 0..7 token-row group
    const int lc   = lane & 7;        // 0..7 expert-col group
    const int row0 = blockIdx.x * MBLK;
    const int kb0  = wv * KCH;

    // W staging: 4 lanes per row (one float4 each), 4 row-groups of 16
    const int sr = lane >> 2;         // 0..15
    const int sc = lane & 3;          // 0..3
    // X staging (32 rows): 2 lanes per row, two float4 each
    const int xr = lane >> 1;         // 0..31
    const int xc = lane & 1;          // 0..1

    float acc[4][8];
#pragma unroll
    for (int i = 0; i < 4; ++i)
#pragma unroll
        for (int j = 0; j < 8; ++j) acc[i][j] = 0.f;

    const float* xb = X + (size_t)row0 * HIDDEN + kb0;
    const float* wb = W + kb0;

    float4 px[2], pw[4];
    px[0] = *(const float4*)(xb + (size_t)xr * HIDDEN + xc * 8);
    px[1] = *(const float4*)(xb + (size_t)xr * HIDDEN + xc * 8 + 4);
#pragma unroll
    for (int it = 0; it < 4; ++it)
        pw[it] = *(const float4*)(wb + (size_t)(it * 16 + sr) * HIDDEN + sc * 4);

#pragma unroll 1
    for (int t = 0; t < NTILE; ++t) {
        // stage this round's tiles (wave-private; DS ops in-order per wave)
        *(float4*)&xs[wv][xr][xc * 8]     = px[0];
        *(float4*)&xs[wv][xr][xc * 8 + 4] = px[1];
#pragma unroll
        for (int it = 0; it < 4; ++it)
            *(float4*)&ws[wv][it * 16 + sr][sc * 4] = pw[it];

        // prefetch next round (vmcnt domain — hides under this round's FMAs)
        if (t + 1 < NTILE) {
            const float* xt = xb + (t + 1) * KBLK;
            const float* wt = wb + (t + 1) * KBLK;
            px[0] = *(const float4*)(xt + (size_t)xr * HIDDEN + xc * 8);
            px[1] = *(const float4*)(xt + (size_t)xr * HIDDEN + xc * 8 + 4);
#pragma unroll
            for (int it = 0; it < 4; ++it)
                pw[it] = *(const float4*)(wt + (size_t)(it * 16 + sr) * HIDDEN + sc * 4);
        }

        // compute: 4 k4-groups; 12 conflict-free ds_read_b128 per 128 FMA-instr
#pragma unroll
        for (int k4 = 0; k4 < 4; ++k4) {
            float4 a[4], b[8];
#pragma unroll
            for (int i = 0; i < 4; ++i)
                a[i] = *(const float4*)&xs[wv][i * 8 + lr][k4 * 4];
#pragma unroll
            for (int j = 0; j < 8; ++j)
                b[j] = *(const float4*)&ws[wv][j * 8 + lc][k4 * 4];
#pragma unroll
            for (int i = 0; i < 4; ++i)
#pragma unroll
                for (int j = 0; j < 8; ++j) {
                    float v = acc[i][j];
                    v = fmaf(a[i].x, b[j].x, v);
                    v = fmaf(a[i].y, b[j].y, v);
                    v = fmaf(a[i].z, b[j].z, v);
                    v = fmaf(a[i].w, b[j].w, v);
                    acc[i][j] = v;
                }
        }
    }

    // ---- cross-chunk reduction, order 0,1,2,3 => ((c0+c1)+c2)+c3 (R1-exact)
    __syncthreads();
    if (wv == 0) {
#pragma unroll
        for (int i = 0; i < 4; ++i)
#pragma unroll
            for (int j = 0; j < 8; ++j)
                red[i * 8 + lr][j * 8 + lc] = acc[i][j];
    }
    __syncthreads();
    for (int c = 1; c < NCHUNK; ++c) {
        if (wv == c) {
#pragma unroll
            for (int i = 0; i < 4; ++i)
#pragma unroll
                for (int j = 0; j < 8; ++j)
                    red[i * 8 + lr][j * 8 + lc] += acc[i][j];
        }
        __syncthreads();
    }

    // ---- routing: one lane per token — identical code to R1
    if (tid < MBLK) {
        const int t = tid;
        float s[NEXP];
        float m = -INFINITY;
#pragma unroll
        for (int e = 0; e < NEXP; ++e) { s[e] = red[t][e]; m = fmaxf(m, s[e]); }
        float sum = 0.f;
#pragma unroll
        for (int e = 0; e < NEXP; ++e) { s[e] = __expf(s[e] - m); sum += s[e]; }
        float inv = 1.f / sum;
#pragma unroll
        for (int e = 0; e < NEXP; ++e) s[e] *= inv;

        float gs[NGROUP];
#pragma unroll
        for (int g = 0; g < NGROUP; ++g) {
            float gm = s[g * 8];
#pragma unroll
            for (int q = 1; q < 8; ++q) gm = fmaxf(gm, s[g * 8 + q]);
            gs[g] = gm;
        }
        unsigned gmask = 0;
        for (int r = 0; r < TOPKG; ++r) {
            int bg = 0; float bv = -INFINITY;
#pragma unroll
            for (int g = 0; g < NGROUP; ++g) {
                bool avail = !((gmask >> g) & 1);
                if (avail && gs[g] > bv) { bv = gs[g]; bg = g; }
            }
            gmask |= 1u << bg;
        }
        unsigned long long chosen = 0ull;
        const int tok = row0 + t;
        for (int k = 0; k < TOPK; ++k) {
            int be = 0; float bv = -INFINITY;
#pragma unroll
            for (int e = 0; e < NEXP; ++e) {
                float v = ((gmask >> (e >> 3)) & 1u) ? s[e] : 0.f;
                bool avail = !((chosen >> e) & 1ull);
                if (avail && v > bv) { bv = v; be = e; }
            }
            chosen |= 1ull << be;
            out[(size_t)tok * TOPK + k] = (float)be;                 // idx as f32
            out[(size_t)half_out + (size_t)tok * TOPK + k] = bv;     // weight
        }
    }
}

extern "C" void kernel_launch(void* const* d_in, const int* in_sizes, int n_in,
                              void* d_out, int out_size, void* d_ws, size_t ws_size,
                              hipStream_t stream)
{
    const float* x = (const float*)d_in[0];
    const float* w = (const float*)d_in[1];
    float* out = (float*)d_out;
    const int half_out = out_size / 2;   // 98304 = 16384*6

    dim3 grid(TOKENS / MBLK);            // 512 blocks -> 2 blocks/CU
    dim3 block(256);                     // 4 waves = 4 K chunks
    moe_gate_kernel<<<grid, block, 0, stream>>>(x, w, out, half_out);
}

// Round 7
// 106.292 us; speedup vs baseline: 1.6280x; 1.2440x over previous
//
#include <hip/hip_runtime.h>
#include <math.h>

#define TOKENS 16384
#define HIDDEN 2048
#define NEXP   64
#define MBLK   64                 // tokens per block (lane = token)
#define NCHUNK 4                  // K chunks — keeps R1 bit-exact logits
#define KCH    512                // k per chunk
#define KBLK   16                 // k per round
#define NTILE  (KCH / KBLK)       // 32 rounds
#define EPG    16                 // experts per wave
#define RPAD   68
#define TOPK   6
#define NGROUP 8
#define TOPKG  3

__global__ __launch_bounds__(1024, 4)
void moe_gate_kernel(const float* __restrict__ X, const float* __restrict__ W,
                     float* __restrict__ out, int half_out)
{
    __shared__ float red[MBLK][RPAD];   // 17408 B — only LDS in the kernel

    const int tid  = threadIdx.x;
    const int wv   = __builtin_amdgcn_readfirstlane(tid >> 6); // 0..15
    const int lane = tid & 63;                                  // = token-in-block
    const int c    = wv >> 2;          // K chunk 0..3
    const int g    = wv & 3;           // expert group 0..3
    const int e0   = g * EPG;
    const int kb0  = c * KCH;
    const int row0 = blockIdx.x * MBLK;

    float acc[EPG];
#pragma unroll
    for (int j = 0; j < EPG; ++j) acc[j] = 0.f;

    // each lane streams ITS token's row directly global->VGPR (64B/round = 1 line)
    const float* xrow = X + (size_t)(row0 + lane) * HIDDEN + kb0;
    // wave-uniform W base -> compiler scalarizes these loads into SGPRs (s_load)
    const float* wb = W + (size_t)e0 * HIDDEN + kb0;

    float4 px[4];
#pragma unroll
    for (int it = 0; it < 4; ++it) px[it] = *(const float4*)(xrow + it * 4);

#pragma unroll 1
    for (int t = 0; t < NTILE; ++t) {
        float4 xq[4];
#pragma unroll
        for (int it = 0; it < 4; ++it) xq[it] = px[it];

        // prefetch next round's x (vmcnt domain; a full round of compute ahead)
        if (t + 1 < NTILE) {
            const float* xn = xrow + (t + 1) * KBLK;
#pragma unroll
            for (int it = 0; it < 4; ++it) px[it] = *(const float4*)(xn + it * 4);
        }

        // 16 experts x 16 k; W operands wave-uniform -> SGPR, x in VGPR.
        // Per expert: k-ascending serial fmaf chain (bit-exact vs R1).
        const float* wk = wb + t * KBLK;
#pragma unroll
        for (int j = 0; j < EPG; ++j) {
            const float4* wr = (const float4*)(wk + (size_t)j * HIDDEN);
            float4 w0 = wr[0], w1 = wr[1], w2 = wr[2], w3 = wr[3];
            float a = acc[j];
            a = fmaf(xq[0].x, w0.x, a); a = fmaf(xq[0].y, w0.y, a);
            a = fmaf(xq[0].z, w0.z, a); a = fmaf(xq[0].w, w0.w, a);
            a = fmaf(xq[1].x, w1.x, a); a = fmaf(xq[1].y, w1.y, a);
            a = fmaf(xq[1].z, w1.z, a); a = fmaf(xq[1].w, w1.w, a);
            a = fmaf(xq[2].x, w2.x, a); a = fmaf(xq[2].y, w2.y, a);
            a = fmaf(xq[2].z, w2.z, a); a = fmaf(xq[2].w, w2.w, a);
            a = fmaf(xq[3].x, w3.x, a); a = fmaf(xq[3].y, w3.y, a);
            a = fmaf(xq[3].z, w3.z, a); a = fmaf(xq[3].w, w3.w, a);
            acc[j] = a;
        }
    }

    // ---- cross-chunk reduction: chunk order 0,1,2,3 => ((c0+c1)+c2)+c3
    // (expert columns disjoint across g; per-column order identical to R1)
    if (c == 0) {
#pragma unroll
        for (int j = 0; j < EPG; ++j) red[lane][e0 + j] = acc[j];
    }
    __syncthreads();
    for (int cc = 1; cc < NCHUNK; ++cc) {
        if (c == cc) {
#pragma unroll
            for (int j = 0; j < EPG; ++j) red[lane][e0 + j] += acc[j];
        }
        __syncthreads();
    }

    // ---- routing: one lane per token — identical code to R1 (proven)
    if (tid < MBLK) {
        const int t = tid;
        float s[NEXP];
        float m = -INFINITY;
#pragma unroll
        for (int e = 0; e < NEXP; ++e) { s[e] = red[t][e]; m = fmaxf(m, s[e]); }
        float sum = 0.f;
#pragma unroll
        for (int e = 0; e < NEXP; ++e) { s[e] = __expf(s[e] - m); sum += s[e]; }
        float inv = 1.f / sum;
#pragma unroll
        for (int e = 0; e < NEXP; ++e) s[e] *= inv;

        float gs[NGROUP];
#pragma unroll
        for (int g2 = 0; g2 < NGROUP; ++g2) {
            float gm = s[g2 * 8];
#pragma unroll
            for (int q = 1; q < 8; ++q) gm = fmaxf(gm, s[g2 * 8 + q]);
            gs[g2] = gm;
        }
        unsigned gmask = 0;
        for (int r = 0; r < TOPKG; ++r) {
            int bg = 0; float bv = -INFINITY;
#pragma unroll
            for (int g2 = 0; g2 < NGROUP; ++g2) {
                bool avail = !((gmask >> g2) & 1);
                if (avail && gs[g2] > bv) { bv = gs[g2]; bg = g2; }
            }
            gmask |= 1u << bg;
        }
        unsigned long long chosen = 0ull;
        const int tok = row0 + t;
        for (int k = 0; k < TOPK; ++k) {
            int be = 0; float bv = -INFINITY;
#pragma unroll
            for (int e = 0; e < NEXP; ++e) {
                float v = ((gmask >> (e >> 3)) & 1u) ? s[e] : 0.f;
                bool avail = !((chosen >> e) & 1ull);
                if (avail && v > bv) { bv = v; be = e; }
            }
            chosen |= 1ull << be;
            out[(size_t)tok * TOPK + k] = (float)be;                 // idx as f32
            out[(size_t)half_out + (size_t)tok * TOPK + k] = bv;     // weight
        }
    }
}

extern "C" void kernel_launch(void* const* d_in, const int* in_sizes, int n_in,
                              void* d_out, int out_size, void* d_ws, size_t ws_size,
                              hipStream_t stream)
{
    const float* x = (const float*)d_in[0];
    const float* w = (const float*)d_in[1];
    float* out = (float*)d_out;
    const int half_out = out_size / 2;   // 98304 = 16384*6

    dim3 grid(TOKENS / MBLK);            // 256 blocks
    dim3 block(1024);                    // 16 waves = 4 chunks x 4 expert-groups
    moe_gate_kernel<<<grid, block, 0, stream>>>(x, w, out, half_out);
}